// Round 3
// baseline (169.881 us; speedup 1.0000x reference)
//
#include <hip/hip_runtime.h>
#include <math.h>

#define EMB_D 64
// ref fp32-rounding band (~1.6e-5) + screen err (bf16-split ~6e-6 + 64-ULP
// pack-trunc ~3.8e-6 => ~1e-5 per score); need >= 3.6e-5, keep 6e-5 (1.7x slack)
#define MARGIN 6.0e-5f
// score bias: biased = 0.5 + (wsq - 2*x.w) in (0.3, 0.7), strictly positive
// => IEEE positive floats compare as uints.  (validated in r2: passed)
#define SBIAS 0.5f

typedef float  f32x4  __attribute__((ext_vector_type(4)));
typedef short  bf16x8 __attribute__((ext_vector_type(8)));

__device__ __forceinline__ unsigned short f2bf(float f) {
    unsigned int u = __float_as_uint(f);
    return (unsigned short)((u + 0x7FFFu + ((u >> 16) & 1u)) >> 16);
}
__device__ __forceinline__ float bf2f(unsigned short h) {
    return __uint_as_float(((unsigned int)h) << 16);
}

union Pack8 { ushort u[8]; bf16x8 v; uint4 q; };

__device__ __forceinline__ bf16x8 ldbf8(const unsigned short* p) {
    union { uint4 u; bf16x8 v; } c;
    c.u = *(const uint4*)p;
    return c.v;
}

// ---------------------------------------------------------------------------
// PREP-W: w -> bf16 hi/lo in MFMA-chunk-transposed order + wsq + zero loss.
// (unchanged, proven)
// ---------------------------------------------------------------------------
__global__ __launch_bounds__(256)
void vq_prepw_kernel(const float* __restrict__ w,
                     unsigned short* __restrict__ wt_hi,
                     unsigned short* __restrict__ wt_lo,
                     float* __restrict__ wsq, float* __restrict__ loss_out,
                     int K) {
    const int i = blockIdx.x * 256 + threadIdx.x;   // chunk id, K*8 total
    if (i == 0) loss_out[0] = 0.f;
    if (i >= K * 8) return;
    const int krow = i >> 3, q = i & 7;
    const int dest = ((krow >> 6) << 9) + (((krow >> 4) & 3) << 7) + (q << 4)
                   + (krow & 15);
    const float* src = w + (size_t)krow * EMB_D + q * 8;
    Pack8 h, l;
#pragma unroll
    for (int j = 0; j < 8; ++j) {
        const float f = src[j];
        h.u[j] = f2bf(f);
        l.u[j] = f2bf(f - bf2f(h.u[j]));
    }
    ((uint4*)wt_hi)[dest] = h.q;
    ((uint4*)wt_lo)[dest] = l.q;

    if (i < K) {   // wsq[i]: numpy-emulated fp32 sum(w_i^2)  [proven]
        const float* wr = w + (size_t)i * EMB_D;
        float r[8];
#pragma unroll
        for (int j = 0; j < 8; ++j) r[j] = __fmul_rn(wr[j], wr[j]);
#pragma unroll
        for (int t = 1; t < 8; ++t)
#pragma unroll
            for (int j = 0; j < 8; ++j)
                r[j] = __fadd_rn(r[j], __fmul_rn(wr[t * 8 + j], wr[t * 8 + j]));
        float a = __fadd_rn(__fadd_rn(r[0], r[1]), __fadd_rn(r[2], r[3]));
        float b = __fadd_rn(__fadd_rn(r[4], r[5]), __fadd_rn(r[6], r[7]));
        wsq[i] = __fadd_rn(a, b);
    }
}

// ---------------------------------------------------------------------------
// FUSED SCREEN + GATHER, v3 (latency-bound fix of r2's 87.7us):
//  - 128-thread blocks (2 waves), 64 rows/block, NB=1024 -> 4 blocks/CU;
//    barrier stalls of one block overlap with 3 independent blocks.
//  - each wave owns 32 rows (2 tiles): B-frag LDS reads still 2x-amortized.
//  - MFMA: two INDEPENDENT 3-chains per tile (r11-proven order, bit-equal
//    scores) instead of r2's serial 6-chain.
//  - LDS 59.4KB -> ~32KB: merge arrays store PACKED uints (score|idx6);
//    k reconstructed from column.  4 blocks/CU fit with margin.
// Selection semantics identical to r2 (passed, absmax 3.8e-6).
// ---------------------------------------------------------------------------
__global__ __launch_bounds__(128, 2)
void vq_fused_kernel(const float* __restrict__ x,
                     const unsigned short* __restrict__ wt_hi,
                     const unsigned short* __restrict__ wt_lo,
                     const float* __restrict__ wsq,
                     const float* __restrict__ w,
                     float* __restrict__ out, float* __restrict__ loss_out,
                     int K, int N, float scale) {
    const int tid  = threadIdx.x;       // 0..127
    const int lane = tid & 63;
    const int wave = tid >> 6;          // 0..1
    const int quad = lane >> 4;
    const int c16  = lane & 15;
    const int rowbase = blockIdx.x * 64 + wave * 32;   // tiles at +0, +16

    __shared__ uint4 sh4[512];              // hi chunks, 8 KB (one 64-k seg)
    __shared__ uint4 sl4[512];              // lo chunks, 8 KB
    __shared__ float wsq_lds[1024];         // biased: wsq + SBIAS (4 KB)
    __shared__ unsigned Mp1[2][32][19];     // packed s1 (4.75 KB)
    __shared__ unsigned Mp2[2][32][19];     // packed s2 (4.75 KB)
    __shared__ int kf[64], strow[64], k2row[64];

    // ---- A-frags: split x hi/lo in-register for both tiles ----
    Pack8 AH0[2], AL0[2], AH1[2], AL1[2];
#pragma unroll
    for (int t = 0; t < 2; ++t) {
        const float* xrow =
            x + (size_t)(rowbase + t * 16 + c16) * EMB_D + quad * 8;
#pragma unroll
        for (int j = 0; j < 8; ++j) {
            const float f0 = xrow[j];
            AH0[t].u[j] = f2bf(f0);
            AL0[t].u[j] = f2bf(f0 - bf2f(AH0[t].u[j]));
            const float f1 = xrow[32 + j];
            AH1[t].u[j] = f2bf(f1);
            AL1[t].u[j] = f2bf(f1 - bf2f(AH1[t].u[j]));
        }
    }

    {   // biased wsq into LDS (global wsq stays unbiased for exact paths)
        float4 a = ((const float4*)wsq)[tid];
        float4 b = ((const float4*)wsq)[128 + tid];
        a.x += SBIAS; a.y += SBIAS; a.z += SBIAS; a.w += SBIAS;
        b.x += SBIAS; b.y += SBIAS; b.z += SBIAS; b.w += SBIAS;
        ((float4*)wsq_lds)[tid]       = a;
        ((float4*)wsq_lds)[128 + tid] = b;
    }

    // packed top-2 per (tile, acc-row)
    unsigned s1v[2][4], s2v[2][4];
#pragma unroll
    for (int t = 0; t < 2; ++t)
#pragma unroll
        for (int i = 0; i < 4; ++i) { s1v[t][i] = 0xFFFFFFFFu; s2v[t][i] = 0xFFFFFFFFu; }

    const uint4* gh = (const uint4*)wt_hi;
    const uint4* gl = (const uint4*)wt_lo;
    uint4 ph[4], pl[4];
#pragma unroll
    for (int j = 0; j < 4; ++j) { ph[j] = gh[j * 128 + tid]; pl[j] = gl[j * 128 + tid]; }

    const int nseg = K >> 6;            // 16
    for (int seg = 0; seg < nseg; ++seg) {
#pragma unroll
        for (int j = 0; j < 4; ++j) {
            sh4[j * 128 + tid] = ph[j];
            sl4[j * 128 + tid] = pl[j];
        }
        __syncthreads();
        if (seg + 1 < nseg) {           // prefetch next segment (coalesced)
            const int b = (seg + 1) * 512;
#pragma unroll
            for (int j = 0; j < 4; ++j) {
                ph[j] = gh[b + j * 128 + tid];
                pl[j] = gl[b + j * 128 + tid];
            }
        }

#pragma unroll
        for (int s = 0; s < 4; ++s) {
            const unsigned short* shp = (const unsigned short*)sh4;
            const unsigned short* slp = (const unsigned short*)sl4;
            const bf16x8 bhi0 = ldbf8(shp + (s * 128 + lane) * 8);
            const bf16x8 bhi1 = ldbf8(shp + (s * 128 + 64 + lane) * 8);
            const bf16x8 blo0 = ldbf8(slp + (s * 128 + lane) * 8);
            const bf16x8 blo1 = ldbf8(slp + (s * 128 + 64 + lane) * 8);
            const float wqb = wsq_lds[seg * 64 + s * 16 + c16];
            const unsigned idx6 = (unsigned)(seg * 4 + s);   // wave-uniform

#pragma unroll
            for (int t = 0; t < 2; ++t) {
                // r11-proven: two independent 3-chains, add at the end
                f32x4 a0 = {0.f, 0.f, 0.f, 0.f};
                f32x4 a1 = {0.f, 0.f, 0.f, 0.f};
                a0 = __builtin_amdgcn_mfma_f32_16x16x32_bf16(AL0[t].v, bhi0, a0, 0, 0, 0);
                a1 = __builtin_amdgcn_mfma_f32_16x16x32_bf16(AL1[t].v, bhi1, a1, 0, 0, 0);
                a0 = __builtin_amdgcn_mfma_f32_16x16x32_bf16(AH0[t].v, blo0, a0, 0, 0, 0);
                a1 = __builtin_amdgcn_mfma_f32_16x16x32_bf16(AH1[t].v, blo1, a1, 0, 0, 0);
                a0 = __builtin_amdgcn_mfma_f32_16x16x32_bf16(AH0[t].v, bhi0, a0, 0, 0, 0);
                a1 = __builtin_amdgcn_mfma_f32_16x16x32_bf16(AH1[t].v, bhi1, a1, 0, 0, 0);
#pragma unroll
                for (int i = 0; i < 4; ++i) {
                    const float sc = fmaf(-2.0f, a0[i] + a1[i], wqb);  // >0
                    const unsigned p =
                        (__float_as_uint(sc) & 0xFFFFFFC0u) | idx6;
                    const unsigned mx = p > s1v[t][i] ? p : s1v[t][i];   // umax
                    s2v[t][i] = s2v[t][i] < mx ? s2v[t][i] : mx;         // umin
                    s1v[t][i] = s1v[t][i] < p  ? s1v[t][i] : p;          // umin
                }
            }
        }
        __syncthreads();
    }

    // ---- cross-residue merge (packed uints; order == r2's c-asc, s1-then-s2) ----
#pragma unroll
    for (int t = 0; t < 2; ++t)
#pragma unroll
        for (int i = 0; i < 4; ++i) {
            const int r32 = t * 16 + quad * 4 + i;
            Mp1[wave][r32][c16] = s1v[t][i];
            Mp2[wave][r32][c16] = s2v[t][i];
        }
    __syncthreads();
    if (tid < 64) {
        const int wv = tid >> 5, r = tid & 31;
        unsigned g1 = 0xFFFFFFFFu, g2 = 0xFFFFFFFFu, g3 = 0xFFFFFFFFu;
        int gk1 = 0, gk2 = 0;
#pragma unroll
        for (int c = 0; c < 16; ++c) {
            {
                const unsigned p = Mp1[wv][r][c];
                if (p < g1)      { g3 = g2; g2 = g1; gk2 = gk1; g1 = p;
                                   gk1 = (int)(((p & 63u) << 4) | (unsigned)c); }
                else if (p < g2) { g3 = g2; g2 = p;
                                   gk2 = (int)(((p & 63u) << 4) | (unsigned)c); }
                else if (p < g3) { g3 = p; }
            }
            {
                const unsigned p = Mp2[wv][r][c];
                if (p < g1)      { g3 = g2; g2 = g1; gk2 = gk1; g1 = p;
                                   gk1 = (int)(((p & 63u) << 4) | (unsigned)c); }
                else if (p < g2) { g3 = g2; g2 = p;
                                   gk2 = (int)(((p & 63u) << 4) | (unsigned)c); }
                else if (p < g3) { g3 = p; }
            }
        }
        kf[tid] = gk1;
        const float f1 = __uint_as_float(g1 & 0xFFFFFFC0u);
        const float f2 = __uint_as_float(g2 & 0xFFFFFFC0u);
        const float f3 = __uint_as_float(g3 & 0xFFFFFFC0u);
        int st = 0;
        if (f2 - f1 <= MARGIN) st = (f3 - f1 > MARGIN) ? 1 : 2;
        strow[tid] = st;
        k2row[tid] = gk2;
    }
    __syncthreads();

    // ---- phase 1: pair rows (r10/r11-proven per-thread exact compare) ----
    if (tid < 64 && strow[tid] == 1) {
        const int row = blockIdx.x * 64 + tid;
        const int ka = kf[tid], kb = k2row[tid];
        const float4* xp = (const float4*)(x + (size_t)row * EMB_D);
        const float4* wa = (const float4*)(w + (size_t)ka * EMB_D);
        const float4* wb = (const float4*)(w + (size_t)kb * EMB_D);
        float r[8];
        double aa0 = 0, aa1 = 0, aa2 = 0, aa3 = 0;
        double ab0 = 0, ab1 = 0, ab2 = 0, ab3 = 0;
#pragma unroll
        for (int q = 0; q < 16; ++q) {
            const float4 xv = xp[q], va = wa[q], vb = wb[q];
            const int j = (q & 1) * 4;
            if (q < 2) {
                r[j + 0] = __fmul_rn(xv.x, xv.x);
                r[j + 1] = __fmul_rn(xv.y, xv.y);
                r[j + 2] = __fmul_rn(xv.z, xv.z);
                r[j + 3] = __fmul_rn(xv.w, xv.w);
            } else {
                r[j + 0] = __fadd_rn(r[j + 0], __fmul_rn(xv.x, xv.x));
                r[j + 1] = __fadd_rn(r[j + 1], __fmul_rn(xv.y, xv.y));
                r[j + 2] = __fadd_rn(r[j + 2], __fmul_rn(xv.z, xv.z));
                r[j + 3] = __fadd_rn(r[j + 3], __fmul_rn(xv.w, xv.w));
            }
            aa0 = fma((double)xv.x, (double)va.x, aa0);
            aa1 = fma((double)xv.y, (double)va.y, aa1);
            aa2 = fma((double)xv.z, (double)va.z, aa2);
            aa3 = fma((double)xv.w, (double)va.w, aa3);
            ab0 = fma((double)xv.x, (double)vb.x, ab0);
            ab1 = fma((double)xv.y, (double)vb.y, ab1);
            ab2 = fma((double)xv.z, (double)vb.z, ab2);
            ab3 = fma((double)xv.w, (double)vb.w, ab3);
        }
        const float xsq = __fadd_rn(
            __fadd_rn(__fadd_rn(r[0], r[1]), __fadd_rn(r[2], r[3])),
            __fadd_rn(__fadd_rn(r[4], r[5]), __fadd_rn(r[6], r[7])));
        const float mfa = (float)((aa0 + aa1) + (aa2 + aa3));
        const float mfb = (float)((ab0 + ab1) + (ab2 + ab3));
        const float sa = __fadd_rn(__fsub_rn(xsq, __fmul_rn(2.0f, mfa)), wsq[ka]);
        const float sb = __fadd_rn(__fsub_rn(xsq, __fmul_rn(2.0f, mfb)), wsq[kb]);
        int win = ka;
        if (sb < sa || (sb == sa && kb < ka)) win = kb;
        kf[tid] = win;
    }
    __syncthreads();

    // ---- phase 2: full rows (rare; proven cooperative body, 2-wave form) ----
    __shared__ float4 xs4[16];
    __shared__ float  xsqs;
    __shared__ float  ls[128];
    __shared__ int    lk[128];
    for (int i = 0; i < 64; ++i) {
        if (strow[i] != 2) continue;                 // block-uniform (LDS)
        const int row = blockIdx.x * 64 + i;
        if (tid < 16) xs4[tid] = ((const float4*)(x + (size_t)row * EMB_D))[tid];
        __syncthreads();
        if (tid == 0) {
            const float* xf = (const float*)xs4;
            float r[8];
#pragma unroll
            for (int j = 0; j < 8; ++j) r[j] = __fmul_rn(xf[j], xf[j]);
#pragma unroll
            for (int t = 1; t < 8; ++t)
#pragma unroll
                for (int j = 0; j < 8; ++j)
                    r[j] = __fadd_rn(r[j], __fmul_rn(xf[t * 8 + j], xf[t * 8 + j]));
            xsqs = __fadd_rn(
                __fadd_rn(__fadd_rn(r[0], r[1]), __fadd_rn(r[2], r[3])),
                __fadd_rn(__fadd_rn(r[4], r[5]), __fadd_rn(r[6], r[7])));
        }
        __syncthreads();
        const float xsq = xsqs;

        float bs = INFINITY;
        int   bk = K;
        for (int t = 0; t < 8; ++t) {
            const int k = t * 128 + tid;             // ascending per thread
            const float4* wr4 = (const float4*)(w + (size_t)k * EMB_D);
            double a0 = 0.0, a1 = 0.0, a2 = 0.0, a3 = 0.0;
#pragma unroll
            for (int q = 0; q < EMB_D / 4; ++q) {
                const float4 xv = xs4[q];
                const float4 wv = wr4[q];
                a0 = fma((double)xv.x, (double)wv.x, a0);
                a1 = fma((double)xv.y, (double)wv.y, a1);
                a2 = fma((double)xv.z, (double)wv.z, a2);
                a3 = fma((double)xv.w, (double)wv.w, a3);
            }
            const float mf = (float)((a0 + a1) + (a2 + a3));
            const float t2 = __fsub_rn(xsq, __fmul_rn(2.0f, mf));
            const float sc = __fadd_rn(t2, wsq[k]);
            if (sc < bs || (sc == bs && k < bk)) { bs = sc; bk = k; }
        }
        ls[tid] = bs; lk[tid] = bk;
        __syncthreads();
        if (wave == 0) {
            float gs = ls[lane];
            int   gk = lk[lane];
            {
                const float os = ls[64 + lane];
                const int   ok = lk[64 + lane];
                if (os < gs || (os == gs && ok < gk)) { gs = os; gk = ok; }
            }
#pragma unroll
            for (int off = 32; off > 0; off >>= 1) {
                const float os = __shfl_down(gs, off);
                const int   ok = __shfl_down(gk, off);
                if (os < gs || (os == gs && ok < gk)) { gs = os; gk = ok; }
            }
            if (lane == 0) kf[i] = gk;
        }
        __syncthreads();
    }

    // ---- phase 3: indices + gather + loss (atomic accumulate) ----
    if (tid < 64) {
        const int row = blockIdx.x * 64 + tid;
        out[(size_t)N * EMB_D + row] = (float)kf[tid];
    }
    float lpart = 0.f;
#pragma unroll
    for (int rep = 0; rep < 8; ++rep) {
        int f4   = rep * 128 + tid;     // 0..1023
        int rr   = f4 >> 4;             // local row 0..63
        int c    = f4 & 15;
        int k    = kf[rr];
        int grow = blockIdx.x * 64 + rr;
        float4 wv = ((const float4*)(w + (size_t)k * EMB_D))[c];
        float4 xq = ((const float4*)(x + (size_t)grow * EMB_D))[c];
        ((float4*)out)[(size_t)grow * (EMB_D / 4) + c] = wv;
        float dx = wv.x - xq.x, dy = wv.y - xq.y;
        float dz = wv.z - xq.z, dw = wv.w - xq.w;
        lpart += dx * dx + dy * dy + dz * dz + dw * dw;
    }
#pragma unroll
    for (int off = 32; off > 0; off >>= 1) lpart += __shfl_down(lpart, off);
    __shared__ float lred[2];
    if (lane == 0) lred[wave] = lpart;
    __syncthreads();
    if (tid == 0)
        atomicAdd(loss_out, (lred[0] + lred[1]) * scale);
}

extern "C" void kernel_launch(void* const* d_in, const int* in_sizes, int n_in,
                              void* d_out, int out_size, void* d_ws, size_t ws_size,
                              hipStream_t stream) {
    const float* x = (const float*)d_in[0];
    const float* w = (const float*)d_in[1];
    float* out = (float*)d_out;
    const int xsz = in_sizes[0];   // N * D
    const int wsz = in_sizes[1];   // K * D
    const int N   = xsz / EMB_D;   // 65536
    const int K   = wsz / EMB_D;   // 1024
    const int NB  = N / 64;        // 1024
    float* loss_out = out + (size_t)N * EMB_D + N;

    // ws: [wsq Kf][wt_hi K*64 u16][wt_lo K*64 u16]
    float* wsq = (float*)d_ws;
    unsigned short* wt_hi = (unsigned short*)(wsq + K);
    unsigned short* wt_lo = wt_hi + (size_t)K * EMB_D;

    vq_prepw_kernel<<<(K * 8 + 255) / 256, 256, 0, stream>>>(w, wt_hi, wt_lo,
                                                             wsq, loss_out, K);
    vq_fused_kernel<<<NB, 128, 0, stream>>>(x, wt_hi, wt_lo, wsq, w, out,
                                            loss_out, K, N,
                                            1.25f / (float)xsz);
}

// Round 4
// 133.026 us; speedup vs baseline: 1.2770x; 1.2770x over previous
//
#include <hip/hip_runtime.h>
#include <math.h>

#define EMB_D 64
// ref fp32-rounding band (~1.6e-5) + screen err (bf16-split ~6e-6 + 64-ULP
// pack-trunc ~3.8e-6 => ~1e-5 per score); need >= 3.6e-5, keep 6e-5 (1.7x slack)
#define MARGIN 6.0e-5f
// score bias: biased = 0.5 + (wsq - 2*x.w) in (0.3, 0.7), strictly positive
// => IEEE positive floats compare as uints.  (validated r2/r3: passed)
#define SBIAS 0.5f

typedef float  f32x4  __attribute__((ext_vector_type(4)));
typedef short  bf16x8 __attribute__((ext_vector_type(8)));

__device__ __forceinline__ unsigned short f2bf(float f) {
    unsigned int u = __float_as_uint(f);
    return (unsigned short)((u + 0x7FFFu + ((u >> 16) & 1u)) >> 16);
}
__device__ __forceinline__ float bf2f(unsigned short h) {
    return __uint_as_float(((unsigned int)h) << 16);
}

union Pack8 { ushort u[8]; bf16x8 v; uint4 q; };

__device__ __forceinline__ bf16x8 ldbf8(const unsigned short* p) {
    union { uint4 u; bf16x8 v; } c;
    c.u = *(const uint4*)p;
    return c.v;
}

// ---------------------------------------------------------------------------
// PREP-W: w -> bf16 hi/lo in MFMA-chunk-transposed order + wsq + zero loss.
// (unchanged, proven)
// ---------------------------------------------------------------------------
__global__ __launch_bounds__(256)
void vq_prepw_kernel(const float* __restrict__ w,
                     unsigned short* __restrict__ wt_hi,
                     unsigned short* __restrict__ wt_lo,
                     float* __restrict__ wsq, float* __restrict__ loss_out,
                     int K) {
    const int i = blockIdx.x * 256 + threadIdx.x;   // chunk id, K*8 total
    if (i == 0) loss_out[0] = 0.f;
    if (i >= K * 8) return;
    const int krow = i >> 3, q = i & 7;
    const int dest = ((krow >> 6) << 9) + (((krow >> 4) & 3) << 7) + (q << 4)
                   + (krow & 15);
    const float* src = w + (size_t)krow * EMB_D + q * 8;
    Pack8 h, l;
#pragma unroll
    for (int j = 0; j < 8; ++j) {
        const float f = src[j];
        h.u[j] = f2bf(f);
        l.u[j] = f2bf(f - bf2f(h.u[j]));
    }
    ((uint4*)wt_hi)[dest] = h.q;
    ((uint4*)wt_lo)[dest] = l.q;

    if (i < K) {   // wsq[i]: numpy-emulated fp32 sum(w_i^2)  [proven]
        const float* wr = w + (size_t)i * EMB_D;
        float r[8];
#pragma unroll
        for (int j = 0; j < 8; ++j) r[j] = __fmul_rn(wr[j], wr[j]);
#pragma unroll
        for (int t = 1; t < 8; ++t)
#pragma unroll
            for (int j = 0; j < 8; ++j)
                r[j] = __fadd_rn(r[j], __fmul_rn(wr[t * 8 + j], wr[t * 8 + j]));
        float a = __fadd_rn(__fadd_rn(r[0], r[1]), __fadd_rn(r[2], r[3]));
        float b = __fadd_rn(__fadd_rn(r[4], r[5]), __fadd_rn(r[6], r[7]));
        wsq[i] = __fadd_rn(a, b);
    }
}

// ---------------------------------------------------------------------------
// FUSED SCREEN + GATHER, v4:
//  - r2 geometry (256 thr / 128 rows / NB=512) + r2's 4xuint4 prefetch
//    (proven no-spill at 87us; r3's 8xuint4 prefetch caused scratch spill ->
//    107MB HBM writes -> traffic-bound 109us).
//  - r3's proven pieces: independent 3-chain MFMAs, packed-uint selection
//    and merge (both passed, absmax 3.8e-6).
//  - NEW: LDS arena overlay — merge arrays (19.5KB) reuse staging buffers
//    (20.5KB, dead after final seg barrier). LDS 59.4KB -> ~26KB =>
//    VGPR-capped 4 blocks/CU (16 waves) instead of r2's ~2 blocks.
// ---------------------------------------------------------------------------
__global__ __launch_bounds__(256, 2)
void vq_fused_kernel(const float* __restrict__ x,
                     const unsigned short* __restrict__ wt_hi,
                     const unsigned short* __restrict__ wt_lo,
                     const float* __restrict__ wsq,
                     const float* __restrict__ w,
                     float* __restrict__ out, float* __restrict__ loss_out,
                     int K, int N, float scale) {
    const int tid  = threadIdx.x;       // 0..255
    const int lane = tid & 63;
    const int wave = tid >> 6;          // 0..3
    const int quad = lane >> 4;
    const int c16  = lane & 15;
    const int rowbase = blockIdx.x * 128 + wave * 32;   // tiles at +0, +16

    // ---- LDS arena: staging (seg loop) overlaid with merge arrays (after) --
    __shared__ __align__(16) char arena[20480];
    uint4* sh4     = (uint4*)arena;             // [512] hi chunks, 8 KB
    uint4* sl4     = (uint4*)(arena + 8192);    // [512] lo chunks, 8 KB
    float* wsq_lds = (float*)(arena + 16384);   // [1024] biased, 4 KB
    typedef unsigned MpArr[32][19];             // [4 waves][32 rows][16+pad]
    MpArr* Mp1 = (MpArr*)arena;                 // 9728 B   (after seg loop)
    MpArr* Mp2 = (MpArr*)(arena + 9728);        // 9728 B   (after seg loop)

    __shared__ int kf[128], strow[128], k2row[128];

    // ---- A-frags: split x hi/lo in-register for both tiles ----
    Pack8 AH0[2], AL0[2], AH1[2], AL1[2];
#pragma unroll
    for (int t = 0; t < 2; ++t) {
        const float* xrow =
            x + (size_t)(rowbase + t * 16 + c16) * EMB_D + quad * 8;
#pragma unroll
        for (int j = 0; j < 8; ++j) {
            const float f0 = xrow[j];
            AH0[t].u[j] = f2bf(f0);
            AL0[t].u[j] = f2bf(f0 - bf2f(AH0[t].u[j]));
            const float f1 = xrow[32 + j];
            AH1[t].u[j] = f2bf(f1);
            AL1[t].u[j] = f2bf(f1 - bf2f(AH1[t].u[j]));
        }
    }

    {   // biased wsq into LDS (global wsq stays unbiased for exact paths)
        float4 a = ((const float4*)wsq)[tid];
        a.x += SBIAS; a.y += SBIAS; a.z += SBIAS; a.w += SBIAS;
        ((float4*)wsq_lds)[tid] = a;
    }

    // packed top-2 per (tile, acc-row)
    unsigned s1v[2][4], s2v[2][4];
#pragma unroll
    for (int t = 0; t < 2; ++t)
#pragma unroll
        for (int i = 0; i < 4; ++i) { s1v[t][i] = 0xFFFFFFFFu; s2v[t][i] = 0xFFFFFFFFu; }

    const uint4* gh = (const uint4*)wt_hi;
    const uint4* gl = (const uint4*)wt_lo;
    uint4 ph0 = gh[tid], ph1 = gh[256 + tid];       // 4x uint4 prefetch
    uint4 pl0 = gl[tid], pl1 = gl[256 + tid];       // (r2-proven, no spill)

    const int nseg = K >> 6;            // 16
    for (int seg = 0; seg < nseg; ++seg) {
        sh4[tid] = ph0; sh4[256 + tid] = ph1;
        sl4[tid] = pl0; sl4[256 + tid] = pl1;
        __syncthreads();
        if (seg + 1 < nseg) {           // prefetch next segment (coalesced)
            const int b = (seg + 1) * 512;
            ph0 = gh[b + tid]; ph1 = gh[b + 256 + tid];
            pl0 = gl[b + tid]; pl1 = gl[b + 256 + tid];
        }

#pragma unroll
        for (int s = 0; s < 4; ++s) {
            const unsigned short* shp = (const unsigned short*)sh4;
            const unsigned short* slp = (const unsigned short*)sl4;
            const bf16x8 bhi0 = ldbf8(shp + (s * 128 + lane) * 8);
            const bf16x8 bhi1 = ldbf8(shp + (s * 128 + 64 + lane) * 8);
            const bf16x8 blo0 = ldbf8(slp + (s * 128 + lane) * 8);
            const bf16x8 blo1 = ldbf8(slp + (s * 128 + 64 + lane) * 8);
            const float wqb = wsq_lds[seg * 64 + s * 16 + c16];
            const unsigned idx6 = (unsigned)(seg * 4 + s);   // wave-uniform

#pragma unroll
            for (int t = 0; t < 2; ++t) {
                // r3-proven: two independent 3-chains, add at the end
                f32x4 a0 = {0.f, 0.f, 0.f, 0.f};
                f32x4 a1 = {0.f, 0.f, 0.f, 0.f};
                a0 = __builtin_amdgcn_mfma_f32_16x16x32_bf16(AL0[t].v, bhi0, a0, 0, 0, 0);
                a1 = __builtin_amdgcn_mfma_f32_16x16x32_bf16(AL1[t].v, bhi1, a1, 0, 0, 0);
                a0 = __builtin_amdgcn_mfma_f32_16x16x32_bf16(AH0[t].v, blo0, a0, 0, 0, 0);
                a1 = __builtin_amdgcn_mfma_f32_16x16x32_bf16(AH1[t].v, blo1, a1, 0, 0, 0);
                a0 = __builtin_amdgcn_mfma_f32_16x16x32_bf16(AH0[t].v, bhi0, a0, 0, 0, 0);
                a1 = __builtin_amdgcn_mfma_f32_16x16x32_bf16(AH1[t].v, bhi1, a1, 0, 0, 0);
#pragma unroll
                for (int i = 0; i < 4; ++i) {
                    const float sc = fmaf(-2.0f, a0[i] + a1[i], wqb);  // >0
                    const unsigned p =
                        (__float_as_uint(sc) & 0xFFFFFFC0u) | idx6;
                    const unsigned mx = p > s1v[t][i] ? p : s1v[t][i];   // umax
                    s2v[t][i] = s2v[t][i] < mx ? s2v[t][i] : mx;         // umin
                    s1v[t][i] = s1v[t][i] < p  ? s1v[t][i] : p;          // umin
                }
            }
        }
        __syncthreads();
    }
    // after the loop's final barrier: sh4/sl4/wsq_lds dead -> overlay Mp1/Mp2

    // ---- cross-residue merge (packed uints; r3-proven semantics) ----
#pragma unroll
    for (int t = 0; t < 2; ++t)
#pragma unroll
        for (int i = 0; i < 4; ++i) {
            const int r32 = t * 16 + quad * 4 + i;
            Mp1[wave][r32][c16] = s1v[t][i];
            Mp2[wave][r32][c16] = s2v[t][i];
        }
    __syncthreads();
    if (tid < 128) {
        const int wv = tid >> 5, r = tid & 31;      // local row lr == tid
        unsigned g1 = 0xFFFFFFFFu, g2 = 0xFFFFFFFFu, g3 = 0xFFFFFFFFu;
        int gk1 = 0, gk2 = 0;
#pragma unroll
        for (int c = 0; c < 16; ++c) {
            {
                const unsigned p = Mp1[wv][r][c];
                if (p < g1)      { g3 = g2; g2 = g1; gk2 = gk1; g1 = p;
                                   gk1 = (int)(((p & 63u) << 4) | (unsigned)c); }
                else if (p < g2) { g3 = g2; g2 = p;
                                   gk2 = (int)(((p & 63u) << 4) | (unsigned)c); }
                else if (p < g3) { g3 = p; }
            }
            {
                const unsigned p = Mp2[wv][r][c];
                if (p < g1)      { g3 = g2; g2 = g1; gk2 = gk1; g1 = p;
                                   gk1 = (int)(((p & 63u) << 4) | (unsigned)c); }
                else if (p < g2) { g3 = g2; g2 = p;
                                   gk2 = (int)(((p & 63u) << 4) | (unsigned)c); }
                else if (p < g3) { g3 = p; }
            }
        }
        kf[tid] = gk1;
        const float f1 = __uint_as_float(g1 & 0xFFFFFFC0u);
        const float f2 = __uint_as_float(g2 & 0xFFFFFFC0u);
        const float f3 = __uint_as_float(g3 & 0xFFFFFFC0u);
        int st = 0;
        if (f2 - f1 <= MARGIN) st = (f3 - f1 > MARGIN) ? 1 : 2;
        strow[tid] = st;
        k2row[tid] = gk2;
    }
    __syncthreads();

    // ---- phase 1: pair rows (r10/r11-proven per-thread exact compare) ----
    if (tid < 128 && strow[tid] == 1) {
        const int row = blockIdx.x * 128 + tid;
        const int ka = kf[tid], kb = k2row[tid];
        const float4* xp = (const float4*)(x + (size_t)row * EMB_D);
        const float4* wa = (const float4*)(w + (size_t)ka * EMB_D);
        const float4* wb = (const float4*)(w + (size_t)kb * EMB_D);
        float r[8];
        double aa0 = 0, aa1 = 0, aa2 = 0, aa3 = 0;
        double ab0 = 0, ab1 = 0, ab2 = 0, ab3 = 0;
#pragma unroll
        for (int q = 0; q < 16; ++q) {
            const float4 xv = xp[q], va = wa[q], vb = wb[q];
            const int j = (q & 1) * 4;
            if (q < 2) {
                r[j + 0] = __fmul_rn(xv.x, xv.x);
                r[j + 1] = __fmul_rn(xv.y, xv.y);
                r[j + 2] = __fmul_rn(xv.z, xv.z);
                r[j + 3] = __fmul_rn(xv.w, xv.w);
            } else {
                r[j + 0] = __fadd_rn(r[j + 0], __fmul_rn(xv.x, xv.x));
                r[j + 1] = __fadd_rn(r[j + 1], __fmul_rn(xv.y, xv.y));
                r[j + 2] = __fadd_rn(r[j + 2], __fmul_rn(xv.z, xv.z));
                r[j + 3] = __fadd_rn(r[j + 3], __fmul_rn(xv.w, xv.w));
            }
            aa0 = fma((double)xv.x, (double)va.x, aa0);
            aa1 = fma((double)xv.y, (double)va.y, aa1);
            aa2 = fma((double)xv.z, (double)va.z, aa2);
            aa3 = fma((double)xv.w, (double)va.w, aa3);
            ab0 = fma((double)xv.x, (double)vb.x, ab0);
            ab1 = fma((double)xv.y, (double)vb.y, ab1);
            ab2 = fma((double)xv.z, (double)vb.z, ab2);
            ab3 = fma((double)xv.w, (double)vb.w, ab3);
        }
        const float xsq = __fadd_rn(
            __fadd_rn(__fadd_rn(r[0], r[1]), __fadd_rn(r[2], r[3])),
            __fadd_rn(__fadd_rn(r[4], r[5]), __fadd_rn(r[6], r[7])));
        const float mfa = (float)((aa0 + aa1) + (aa2 + aa3));
        const float mfb = (float)((ab0 + ab1) + (ab2 + ab3));
        const float sa = __fadd_rn(__fsub_rn(xsq, __fmul_rn(2.0f, mfa)), wsq[ka]);
        const float sb = __fadd_rn(__fsub_rn(xsq, __fmul_rn(2.0f, mfb)), wsq[kb]);
        int win = ka;
        if (sb < sa || (sb == sa && kb < ka)) win = kb;
        kf[tid] = win;
    }
    __syncthreads();

    // ---- phase 2: full rows (rare; r2-proven 4-wave cooperative body) ----
    __shared__ float4 xs4[16];
    __shared__ float  xsqs;
    __shared__ float  ls[256];
    __shared__ int    lk[256];
    for (int i = 0; i < 128; ++i) {
        if (strow[i] != 2) continue;                 // block-uniform (LDS)
        const int row = blockIdx.x * 128 + i;
        if (tid < 16) xs4[tid] = ((const float4*)(x + (size_t)row * EMB_D))[tid];
        __syncthreads();
        if (tid == 0) {
            const float* xf = (const float*)xs4;
            float r[8];
#pragma unroll
            for (int j = 0; j < 8; ++j) r[j] = __fmul_rn(xf[j], xf[j]);
#pragma unroll
            for (int t = 1; t < 8; ++t)
#pragma unroll
                for (int j = 0; j < 8; ++j)
                    r[j] = __fadd_rn(r[j], __fmul_rn(xf[t * 8 + j], xf[t * 8 + j]));
            xsqs = __fadd_rn(
                __fadd_rn(__fadd_rn(r[0], r[1]), __fadd_rn(r[2], r[3])),
                __fadd_rn(__fadd_rn(r[4], r[5]), __fadd_rn(r[6], r[7])));
        }
        __syncthreads();
        const float xsq = xsqs;

        float bs = INFINITY;
        int   bk = K;
        for (int t = 0; t < 4; ++t) {
            const int k = wave * (K >> 2) + t * 64 + lane;
            const float4* wr4 = (const float4*)(w + (size_t)k * EMB_D);
            double a0 = 0.0, a1 = 0.0, a2 = 0.0, a3 = 0.0;
#pragma unroll
            for (int q = 0; q < EMB_D / 4; ++q) {
                const float4 xv = xs4[q];
                const float4 wv = wr4[q];
                a0 = fma((double)xv.x, (double)wv.x, a0);
                a1 = fma((double)xv.y, (double)wv.y, a1);
                a2 = fma((double)xv.z, (double)wv.z, a2);
                a3 = fma((double)xv.w, (double)wv.w, a3);
            }
            const float mf = (float)((a0 + a1) + (a2 + a3));
            const float t2 = __fsub_rn(xsq, __fmul_rn(2.0f, mf));
            const float sc = __fadd_rn(t2, wsq[k]);
            if (sc < bs || (sc == bs && k < bk)) { bs = sc; bk = k; }
        }
        ls[tid] = bs; lk[tid] = bk;
        __syncthreads();
        if (wave == 0) {
            float gs = ls[lane];
            int   gk = lk[lane];
#pragma unroll
            for (int c = 1; c < 4; ++c) {
                const float os = ls[c * 64 + lane];
                const int   ok = lk[c * 64 + lane];
                if (os < gs || (os == gs && ok < gk)) { gs = os; gk = ok; }
            }
#pragma unroll
            for (int off = 32; off > 0; off >>= 1) {
                const float os = __shfl_down(gs, off);
                const int   ok = __shfl_down(gk, off);
                if (os < gs || (os == gs && ok < gk)) { gs = os; gk = ok; }
            }
            if (lane == 0) kf[i] = gk;
        }
        __syncthreads();
    }

    // ---- phase 3: indices + gather + loss (atomic accumulate) ----
    if (tid < 128) {
        const int row = blockIdx.x * 128 + tid;
        out[(size_t)N * EMB_D + row] = (float)kf[tid];
    }
    float lpart = 0.f;
#pragma unroll
    for (int rep = 0; rep < 8; ++rep) {
        int f4   = rep * 256 + tid;     // 0..2047
        int rr   = f4 >> 4;             // local row 0..127
        int c    = f4 & 15;
        int k    = kf[rr];
        int grow = blockIdx.x * 128 + rr;
        float4 wv = ((const float4*)(w + (size_t)k * EMB_D))[c];
        float4 xq = ((const float4*)(x + (size_t)grow * EMB_D))[c];
        ((float4*)out)[(size_t)grow * (EMB_D / 4) + c] = wv;
        float dx = wv.x - xq.x, dy = wv.y - xq.y;
        float dz = wv.z - xq.z, dw = wv.w - xq.w;
        lpart += dx * dx + dy * dy + dz * dz + dw * dw;
    }
#pragma unroll
    for (int off = 32; off > 0; off >>= 1) lpart += __shfl_down(lpart, off);
    __shared__ float lred[4];
    if (lane == 0) lred[wave] = lpart;
    __syncthreads();
    if (tid == 0)
        atomicAdd(loss_out, ((lred[0] + lred[1]) + (lred[2] + lred[3])) * scale);
}

extern "C" void kernel_launch(void* const* d_in, const int* in_sizes, int n_in,
                              void* d_out, int out_size, void* d_ws, size_t ws_size,
                              hipStream_t stream) {
    const float* x = (const float*)d_in[0];
    const float* w = (const float*)d_in[1];
    float* out = (float*)d_out;
    const int xsz = in_sizes[0];   // N * D
    const int wsz = in_sizes[1];   // K * D
    const int N   = xsz / EMB_D;   // 65536
    const int K   = wsz / EMB_D;   // 1024
    const int NB  = N / 128;       // 512
    float* loss_out = out + (size_t)N * EMB_D + N;

    // ws: [wsq Kf][wt_hi K*64 u16][wt_lo K*64 u16]
    float* wsq = (float*)d_ws;
    unsigned short* wt_hi = (unsigned short*)(wsq + K);
    unsigned short* wt_lo = wt_hi + (size_t)K * EMB_D;

    vq_prepw_kernel<<<(K * 8 + 255) / 256, 256, 0, stream>>>(w, wt_hi, wt_lo,
                                                             wsq, loss_out, K);
    vq_fused_kernel<<<NB, 256, 0, stream>>>(x, wt_hi, wt_lo, wsq, w, out,
                                            loss_out, K, N,
                                            1.25f / (float)xsz);
}